// Round 7
// baseline (433.725 us; speedup 1.0000x reference)
//
#include <hip/hip_runtime.h>
#include <stdint.h>

typedef short s16x8 __attribute__((ext_vector_type(8)));
typedef unsigned short u16x8 __attribute__((ext_vector_type(8)));
typedef float f32x4 __attribute__((ext_vector_type(4)));

#define XPAD_BYTES ((size_t)(32 * 58 * 58 * 128) * 2)

// xpad layout: [n][row 0..57][cseg 0..15][col 0..57][8c]  (16B chunk = 8 c's)
// wq   layout: [kk 0..8][cseg 0..15][o 0..255][8c]

static __device__ __forceinline__ unsigned short f2bf(float f) {
    union { float f; uint32_t u; } v; v.f = f;
    uint32_t r = v.u + 0x7FFFu + ((v.u >> 16) & 1u);
    return (unsigned short)(r >> 16);
}

static __device__ __forceinline__ s16x8 ldfrag(const unsigned short* p) {
    return *(const s16x8*)p;
}

static __device__ __forceinline__ void gload16(const unsigned short* g, unsigned short* l) {
    __builtin_amdgcn_global_load_lds(
        (const __attribute__((address_space(1))) uint32_t*)g,
        (__attribute__((address_space(3))) uint32_t*)l, 16, 0, 0);
}

// ---------------- weight quantization -> [kk][cseg][o][8] ----------------
__global__ void quant_k(const float* __restrict__ pc,
                        const float* __restrict__ ql,
                        unsigned short* __restrict__ wq) {
    int p = blockIdx.x * 256 + threadIdx.x;
    if (p >= 9 * 16 * 256 * 8) return;
    int j = p & 7;
    int o = (p >> 3) & 255;
    int cs = (p >> 11) & 15;
    int kk = p >> 15;
    int c = cs * 8 + j;
    const float* v = pc + ((size_t)((o * 128 + c) * 9 + kk) * 7);
    float vv[7];
    float s = 0.f;
#pragma unroll
    for (int l = 0; l < 7; ++l) { vv[l] = v[l]; s += vv[l] * vv[l]; }
    float norm = sqrtf(s);
    float best = 10.0f * (vv[0] / norm);
    int bi = 0;
#pragma unroll
    for (int l = 1; l < 7; ++l) {
        float t = 10.0f * (vv[l] / norm);
        if (t > best) { best = t; bi = l; }
    }
    wq[p] = f2bf(ql[bi]);
}

// ---------------- zero the halo border of xpad ----------------
__global__ void border_k(unsigned short* __restrict__ xpad) {
    int i = blockIdx.x * 256 + threadIdx.x;   // 456*256 = 116736 = 32*3648
    const u16x8 z = (u16x8){0, 0, 0, 0, 0, 0, 0, 0};
    int n = i / 3648;
    int rem = i - n * 3648;
    int r, cs, col;
    if (rem < 1856) {
        int rt = rem / 928;
        int q = rem - rt * 928;
        r = rt * 57;
        cs = q / 58;
        col = q - cs * 58;
    } else {
        int rem2 = rem - 1856;
        int ct = rem2 / 896;
        int q = rem2 - ct * 896;
        col = ct * 57;
        cs = q / 56;
        r = 1 + (q - cs * 56);
    }
    *(u16x8*)(xpad + ((((size_t)n * 58 + r) * 16 + cs) * 58 + col) * 8) = z;
}

// ---------------- x: NCHW f32 -> padded [n][row][cseg][col][8] bf16 ----------------
__global__ __launch_bounds__(256) void xform_k(const float* __restrict__ x,
                                               unsigned short* __restrict__ xpad) {
    const int h = blockIdx.x;
    const int n = blockIdx.y;
    const int t = threadIdx.x;
    if (t >= 224) return;
    int cgrp = t / 56;
    int w = t - cgrp * 56;
#pragma unroll
    for (int seg = 0; seg < 4; ++seg) {
        int cs = seg * 4 + cgrp;
        const float* src = x + ((size_t)(n * 128 + cs * 8) * 56 + h) * 56 + w;
        u16x8 d;
#pragma unroll
        for (int jj = 0; jj < 8; ++jj)
            d[jj] = f2bf(src[(size_t)jj * 3136]);
        *(u16x8*)(xpad + ((((size_t)n * 58 + h + 1) * 16 + cs) * 58 + (w + 1)) * 8) = d;
    }
}

// ---------------- implicit-GEMM conv: x LDS (dbuf, shared by 128 o), weights global->reg ----------------
// Block: 128 o x (8 rows x 56) = 448 spatial, 512 threads = 8 waves.
// Wave (oh = wave>>2, sq = wave&3): 64 o (oh half) x 112 spatial (sq quarter).
// LDS xs[buf]: [cseg_rel 0..3][pos 0..607 (580 used)] 16B chunks -> 38912 B/buf.
// __launch_bounds__(512,4): VGPR cap 128 (acc 112 + ~16 working, proven by conv5)
// -> 2 blocks/CU (LDS 77824*2 = 155648 <= 163840), 16 waves/CU, 4 waves/SIMD.
__global__ __launch_bounds__(512, 4) void conv6_k(const unsigned short* __restrict__ xpad,
                                                  const unsigned short* __restrict__ wq,
                                                  float* __restrict__ out) {
    __shared__ __align__(16) unsigned short xs[2][2432 * 8];   // 77824 B total

    const int tid = threadIdx.x;
    const int h0 = blockIdx.x * 8;
    const int n = blockIdx.y;
    const int o0 = blockIdx.z * 128;
    const int lane = tid & 63;
    const int wave = tid >> 6;     // 0..7
    const int oh = wave >> 2;      // 0..1
    const int sq = wave & 3;       // 0..3
    const int l16 = lane & 15;
    const int kgrp = lane >> 4;

    // ---- x staging source offsets (chunk-0; chunk t adds t*1856 elems) ----
    int offx[5];
#pragma unroll
    for (int i = 0; i < 5; ++i) {
        int ci = i * 512 + tid;          // 0..2559
        int ce = ci < 2432 ? ci : 0;
        int cs = ce / 608;               // relative cseg 0..3
        int pos = ce - cs * 608;
        int pe = pos < 580 ? pos : 579;  // clamp pad chunks to valid addr
        int r = pe / 58;
        int col = pe - r * 58;
        offx[i] = (((n * 58 + h0 + r) * 16 + cs) * 58 + col) * 8;
    }
    const bool v4 = wave < 6;            // i=4: chunks 2048..2431 only (waves 0..5)

    // ---- B-fragment LDS bases ----
    int bb[7];
#pragma unroll
    for (int f = 0; f < 7; ++f) {
        int s = sq * 112 + f * 16 + l16;     // 0..447
        int r = s / 56;
        int w = s - r * 56;
        bb[f] = (kgrp * 608 + r * 58 + w) * 8;
    }

    // ---- A-fragment global base: A(kk,t,of) = wA + kk*32768 + t*8192 + of*128 ----
    const unsigned short* wA = wq + (size_t)(kgrp * 256 + o0 + oh * 64 + l16) * 8;

    f32x4 acc[4][7];
#pragma unroll
    for (int a = 0; a < 4; ++a)
#pragma unroll
        for (int f = 0; f < 7; ++f) acc[a][f] = (f32x4){0.f, 0.f, 0.f, 0.f};

    // ---- prologue: stage chunk 0 into buf 0 ----
#pragma unroll
    for (int i = 0; i < 4; ++i)
        gload16(xpad + offx[i], &xs[0][(i * 512 + wave * 64) * 8]);
    if (v4)
        gload16(xpad + offx[4], &xs[0][(2048 + wave * 64) * 8]);
    __syncthreads();

#pragma unroll
    for (int t = 0; t < 4; ++t) {
        const int cur = t & 1;
        if (t < 3) {
            const int xoff = (t + 1) * 1856;
#pragma unroll
            for (int i = 0; i < 4; ++i)
                gload16(xpad + offx[i] + xoff, &xs[cur ^ 1][(i * 512 + wave * 64) * 8]);
            if (v4)
                gload16(xpad + offx[4] + xoff, &xs[cur ^ 1][(2048 + wave * 64) * 8]);
        }

        const unsigned short* xsb = xs[cur];

        s16x8 A0[4], A1[4];
#pragma unroll
        for (int of = 0; of < 4; ++of)
            A0[of] = ldfrag(wA + t * 8192 + of * 128);

#pragma unroll
        for (int kk = 0; kk < 9; ++kk) {
            s16x8 Ac[4];
#pragma unroll
            for (int of = 0; of < 4; ++of) Ac[of] = (kk & 1) ? A1[of] : A0[of];
            if (kk < 8) {
#pragma unroll
                for (int of = 0; of < 4; ++of) {
                    s16x8 vld = ldfrag(wA + (kk + 1) * 32768 + t * 8192 + of * 128);
                    if (kk & 1) A0[of] = vld; else A1[of] = vld;
                }
            }
            const int kh = kk / 3;
            const int kw = kk - kh * 3;
            const int xo = (kh * 58 + kw) * 8;
#pragma unroll
            for (int f = 0; f < 7; ++f) {
                s16x8 b = ldfrag(xsb + bb[f] + xo);
                acc[0][f] = __builtin_amdgcn_mfma_f32_16x16x32_bf16(Ac[0], b, acc[0][f], 0, 0, 0);
                acc[1][f] = __builtin_amdgcn_mfma_f32_16x16x32_bf16(Ac[1], b, acc[1][f], 0, 0, 0);
                acc[2][f] = __builtin_amdgcn_mfma_f32_16x16x32_bf16(Ac[2], b, acc[2][f], 0, 0, 0);
                acc[3][f] = __builtin_amdgcn_mfma_f32_16x16x32_bf16(Ac[3], b, acc[3][f], 0, 0, 0);
            }
        }
        __syncthreads();
    }

    // ---- epilogue (mapping verified rounds 1-6) ----
#pragma unroll
    for (int of = 0; of < 4; ++of) {
        int ob = o0 + oh * 64 + of * 16 + kgrp * 4;
#pragma unroll
        for (int f = 0; f < 7; ++f) {
            int s = sq * 112 + f * 16 + l16;
            int r = s / 56;
            int w = s - r * 56;
            int h = h0 + r;
            float* dst = out + ((size_t)(n * 256 + ob) * 56 + h) * 56 + w;
#pragma unroll
            for (int j = 0; j < 4; ++j) dst[(size_t)j * 3136] = acc[of][f][j];
        }
    }
}

extern "C" void kernel_launch(void* const* d_in, const int* in_sizes, int n_in,
                              void* d_out, int out_size, void* d_ws, size_t ws_size,
                              hipStream_t stream) {
    const float* x = (const float*)d_in[0];
    const float* pc = (const float*)d_in[1];
    const float* ql = (const float*)d_in[2];
    float* out = (float*)d_out;

    unsigned short* xpad = (unsigned short*)d_ws;
    unsigned short* wq = (unsigned short*)((char*)d_ws + XPAD_BYTES);

    border_k<<<456, 256, 0, stream>>>(xpad);
    quant_k<<<1152, 256, 0, stream>>>(pc, ql, wq);
    xform_k<<<dim3(56, 32), 256, 0, stream>>>(x, xpad);
    conv6_k<<<dim3(7, 32, 2), 512, 0, stream>>>(xpad, wq, out);
}

// Round 8
// 93.712 us; speedup vs baseline: 4.6283x; 4.6283x over previous
//
#include <hip/hip_runtime.h>
#include <stdint.h>

typedef short s16x8 __attribute__((ext_vector_type(8)));
typedef unsigned short u16x8 __attribute__((ext_vector_type(8)));
typedef float f32x4 __attribute__((ext_vector_type(4)));

#define XPAD_BYTES ((size_t)(32 * 58 * 58 * 128) * 2)

// xpad layout: [n][row 0..57][cseg 0..15][col 0..57][8c]  (16B chunk = 8 c's)
// wq   layout: [kk 0..8][cseg 0..15][o 0..255][8c]

static __device__ __forceinline__ unsigned short f2bf(float f) {
    union { float f; uint32_t u; } v; v.f = f;
    uint32_t r = v.u + 0x7FFFu + ((v.u >> 16) & 1u);
    return (unsigned short)(r >> 16);
}

static __device__ __forceinline__ s16x8 ldfrag(const unsigned short* p) {
    return *(const s16x8*)p;
}

static __device__ __forceinline__ void gload16(const unsigned short* g, unsigned short* l) {
    __builtin_amdgcn_global_load_lds(
        (const __attribute__((address_space(1))) uint32_t*)g,
        (__attribute__((address_space(3))) uint32_t*)l, 16, 0, 0);
}

// ---------------- weight quantization -> [kk][cseg][o][8] ----------------
__global__ void quant_k(const float* __restrict__ pc,
                        const float* __restrict__ ql,
                        unsigned short* __restrict__ wq) {
    int p = blockIdx.x * 256 + threadIdx.x;
    if (p >= 9 * 16 * 256 * 8) return;
    int j = p & 7;
    int o = (p >> 3) & 255;
    int cs = (p >> 11) & 15;
    int kk = p >> 15;
    int c = cs * 8 + j;
    const float* v = pc + ((size_t)((o * 128 + c) * 9 + kk) * 7);
    float vv[7];
    float s = 0.f;
#pragma unroll
    for (int l = 0; l < 7; ++l) { vv[l] = v[l]; s += vv[l] * vv[l]; }
    float norm = sqrtf(s);
    float best = 10.0f * (vv[0] / norm);
    int bi = 0;
#pragma unroll
    for (int l = 1; l < 7; ++l) {
        float t = 10.0f * (vv[l] / norm);
        if (t > best) { best = t; bi = l; }
    }
    wq[p] = f2bf(ql[bi]);
}

// ---------------- zero the halo border of xpad ----------------
__global__ void border_k(unsigned short* __restrict__ xpad) {
    int i = blockIdx.x * 256 + threadIdx.x;   // 456*256 = 116736 = 32*3648
    const u16x8 z = (u16x8){0, 0, 0, 0, 0, 0, 0, 0};
    int n = i / 3648;
    int rem = i - n * 3648;
    int r, cs, col;
    if (rem < 1856) {
        int rt = rem / 928;
        int q = rem - rt * 928;
        r = rt * 57;
        cs = q / 58;
        col = q - cs * 58;
    } else {
        int rem2 = rem - 1856;
        int ct = rem2 / 896;
        int q = rem2 - ct * 896;
        col = ct * 57;
        cs = q / 56;
        r = 1 + (q - cs * 56);
    }
    *(u16x8*)(xpad + ((((size_t)n * 58 + r) * 16 + cs) * 58 + col) * 8) = z;
}

// ---------------- x: NCHW f32 -> padded [n][row][cseg][col][8] bf16 ----------------
__global__ __launch_bounds__(256) void xform_k(const float* __restrict__ x,
                                               unsigned short* __restrict__ xpad) {
    const int h = blockIdx.x;
    const int n = blockIdx.y;
    const int t = threadIdx.x;
    if (t >= 224) return;
    int cgrp = t / 56;
    int w = t - cgrp * 56;
#pragma unroll
    for (int seg = 0; seg < 4; ++seg) {
        int cs = seg * 4 + cgrp;
        const float* src = x + ((size_t)(n * 128 + cs * 8) * 56 + h) * 56 + w;
        u16x8 d;
#pragma unroll
        for (int jj = 0; jj < 8; ++jj)
            d[jj] = f2bf(src[(size_t)jj * 3136]);
        *(u16x8*)(xpad + ((((size_t)n * 58 + h + 1) * 16 + cs) * 58 + (w + 1)) * 8) = d;
    }
}

// ---------------- implicit-GEMM conv: x LDS (dbuf, shared by 128 o), weights global->reg ----------------
// Block: 128 o x (8 rows x 56) = 448 spatial, 512 threads = 8 waves.
// Wave (oh = wave>>2, sq = wave&3): 64 o (oh half) x 112 spatial (sq quarter).
// LDS xs[buf]: [cseg_rel 0..3][pos 0..607 (580 used)] 16B chunks -> 38912 B/buf.
// __launch_bounds__(512,2): allocator budget 256/2 = 128 VGPR (fits 112 acc +
// working set, proven by conv5 which compiled to exactly 128). Runtime still
// co-schedules 2 blocks/CU (128 VGPR -> 16 waves/CU; LDS 2x77824 <= 163840).
// NOTE (r6/r7): budget is 256/min_waves -> (512,3)=84, (512,4)=64 = acc spill.
__global__ __launch_bounds__(512, 2) void conv6_k(const unsigned short* __restrict__ xpad,
                                                  const unsigned short* __restrict__ wq,
                                                  float* __restrict__ out) {
    __shared__ __align__(16) unsigned short xs[2][2432 * 8];   // 77824 B total

    const int tid = threadIdx.x;
    const int h0 = blockIdx.x * 8;
    const int n = blockIdx.y;
    const int o0 = blockIdx.z * 128;
    const int lane = tid & 63;
    const int wave = tid >> 6;     // 0..7
    const int oh = wave >> 2;      // 0..1
    const int sq = wave & 3;       // 0..3
    const int l16 = lane & 15;
    const int kgrp = lane >> 4;

    // ---- x staging source offsets (chunk-0; chunk t adds t*1856 elems) ----
    int offx[5];
#pragma unroll
    for (int i = 0; i < 5; ++i) {
        int ci = i * 512 + tid;          // 0..2559
        int ce = ci < 2432 ? ci : 0;
        int cs = ce / 608;               // relative cseg 0..3
        int pos = ce - cs * 608;
        int pe = pos < 580 ? pos : 579;  // clamp pad chunks to valid addr
        int r = pe / 58;
        int col = pe - r * 58;
        offx[i] = (((n * 58 + h0 + r) * 16 + cs) * 58 + col) * 8;
    }
    const bool v4 = wave < 6;            // i=4: chunks 2048..2431 only (waves 0..5)

    // ---- B-fragment LDS bases ----
    int bb[7];
#pragma unroll
    for (int f = 0; f < 7; ++f) {
        int s = sq * 112 + f * 16 + l16;     // 0..447
        int r = s / 56;
        int w = s - r * 56;
        bb[f] = (kgrp * 608 + r * 58 + w) * 8;
    }

    // ---- A-fragment global base: A(kk,t,of) = wA + kk*32768 + t*8192 + of*128 ----
    const unsigned short* wA = wq + (size_t)(kgrp * 256 + o0 + oh * 64 + l16) * 8;

    f32x4 acc[4][7];
#pragma unroll
    for (int a = 0; a < 4; ++a)
#pragma unroll
        for (int f = 0; f < 7; ++f) acc[a][f] = (f32x4){0.f, 0.f, 0.f, 0.f};

    // ---- prologue: stage chunk 0 into buf 0 ----
#pragma unroll
    for (int i = 0; i < 4; ++i)
        gload16(xpad + offx[i], &xs[0][(i * 512 + wave * 64) * 8]);
    if (v4)
        gload16(xpad + offx[4], &xs[0][(2048 + wave * 64) * 8]);
    __syncthreads();

#pragma unroll
    for (int t = 0; t < 4; ++t) {
        const int cur = t & 1;
        if (t < 3) {
            const int xoff = (t + 1) * 1856;
#pragma unroll
            for (int i = 0; i < 4; ++i)
                gload16(xpad + offx[i] + xoff, &xs[cur ^ 1][(i * 512 + wave * 64) * 8]);
            if (v4)
                gload16(xpad + offx[4] + xoff, &xs[cur ^ 1][(2048 + wave * 64) * 8]);
        }

        const unsigned short* xsb = xs[cur];

        s16x8 A0[4], A1[4];
#pragma unroll
        for (int of = 0; of < 4; ++of)
            A0[of] = ldfrag(wA + t * 8192 + of * 128);

#pragma unroll
        for (int kk = 0; kk < 9; ++kk) {
            s16x8 Ac[4];
#pragma unroll
            for (int of = 0; of < 4; ++of) Ac[of] = (kk & 1) ? A1[of] : A0[of];
            if (kk < 8) {
#pragma unroll
                for (int of = 0; of < 4; ++of) {
                    s16x8 vld = ldfrag(wA + (kk + 1) * 32768 + t * 8192 + of * 128);
                    if (kk & 1) A0[of] = vld; else A1[of] = vld;
                }
            }
            const int kh = kk / 3;
            const int kw = kk - kh * 3;
            const int xo = (kh * 58 + kw) * 8;
#pragma unroll
            for (int f = 0; f < 7; ++f) {
                s16x8 b = ldfrag(xsb + bb[f] + xo);
                acc[0][f] = __builtin_amdgcn_mfma_f32_16x16x32_bf16(Ac[0], b, acc[0][f], 0, 0, 0);
                acc[1][f] = __builtin_amdgcn_mfma_f32_16x16x32_bf16(Ac[1], b, acc[1][f], 0, 0, 0);
                acc[2][f] = __builtin_amdgcn_mfma_f32_16x16x32_bf16(Ac[2], b, acc[2][f], 0, 0, 0);
                acc[3][f] = __builtin_amdgcn_mfma_f32_16x16x32_bf16(Ac[3], b, acc[3][f], 0, 0, 0);
            }
        }
        __syncthreads();
    }

    // ---- epilogue (mapping verified rounds 1-7) ----
#pragma unroll
    for (int of = 0; of < 4; ++of) {
        int ob = o0 + oh * 64 + of * 16 + kgrp * 4;
#pragma unroll
        for (int f = 0; f < 7; ++f) {
            int s = sq * 112 + f * 16 + l16;
            int r = s / 56;
            int w = s - r * 56;
            int h = h0 + r;
            float* dst = out + ((size_t)(n * 256 + ob) * 56 + h) * 56 + w;
#pragma unroll
            for (int j = 0; j < 4; ++j) dst[(size_t)j * 3136] = acc[of][f][j];
        }
    }
}

extern "C" void kernel_launch(void* const* d_in, const int* in_sizes, int n_in,
                              void* d_out, int out_size, void* d_ws, size_t ws_size,
                              hipStream_t stream) {
    const float* x = (const float*)d_in[0];
    const float* pc = (const float*)d_in[1];
    const float* ql = (const float*)d_in[2];
    float* out = (float*)d_out;

    unsigned short* xpad = (unsigned short*)d_ws;
    unsigned short* wq = (unsigned short*)((char*)d_ws + XPAD_BYTES);

    border_k<<<456, 256, 0, stream>>>(xpad);
    quant_k<<<1152, 256, 0, stream>>>(pc, ql, wq);
    xform_k<<<dim3(56, 32), 256, 0, stream>>>(x, xpad);
    conv6_k<<<dim3(7, 32, 2), 512, 0, stream>>>(xpad, wq, out);
}